// Round 6
// baseline (455.777 us; speedup 1.0000x reference)
//
#include <hip/hip_runtime.h>
#include <hip/hip_bf16.h>

// GCN_85804856639970 — 2-layer GCN + FC head, MI355X.
// N=50000, E=800000, 128->128->64, head 64x64. fp32 in/out, edge_index int32.
//
// R6: fused pipeline, 8 dispatches:
//   memset(degi) -> count -> single-block scan -> fill(col) -> wt_all
//   -> mgemm1 (x@W1 *dinv, bf16 hs1)
//   -> fused1 (CSR-gather hs1 + relu epilogue -> LDS -> MFMA @W2 *dinv -> bf16 hs2)
//   -> fused2 (CSR-gather hs2 + relu epilogue -> LDS -> MFMA @fcW + fcb -> fp32 out)

typedef __attribute__((ext_vector_type(8))) short bf16x8;
typedef __attribute__((ext_vector_type(4))) float f32x4;

__device__ __forceinline__ unsigned short f2bf(float f) {
    unsigned u = __float_as_uint(f);
    unsigned r = (u + 0x7FFFu + ((u >> 16) & 1u)) >> 16;
    return (unsigned short)r;
}
__device__ __forceinline__ float bf16_lo(unsigned u) {
    return __uint_as_float((u & 0xFFFFu) << 16);
}
__device__ __forceinline__ float bf16_hi(unsigned u) {
    return __uint_as_float(u & 0xFFFF0000u);
}
__device__ __forceinline__ float bf16_one(unsigned short u) {
    return __uint_as_float(((unsigned)u) << 16);
}

// ---------------- CSR build ----------------

__global__ void k_count(const int* __restrict__ dst, int e, int* __restrict__ degi) {
    int i = blockIdx.x * blockDim.x + threadIdx.x;
    if (i < e) atomicAdd(&degi[dst[i]], 1);
}

// Single-block scan: rowptr (inclusive prefix shifted), cursor (exclusive), dinv.
__global__ __launch_bounds__(1024) void k_scan_all(
    const int* __restrict__ degi, int* __restrict__ rowptr,
    int* __restrict__ cursor, float* __restrict__ dinv, int n) {
    __shared__ int s[1024];
    int t = threadIdx.x;
    int ce = (n + 1023) >> 10;
    int lo = t * ce;
    int hi = min(lo + ce, n);
    int sum = 0;
    for (int i = lo; i < hi; ++i) sum += degi[i];
    s[t] = sum;
    __syncthreads();
#pragma unroll
    for (int off = 1; off < 1024; off <<= 1) {
        int v = (t >= off) ? s[t - off] : 0;
        __syncthreads();
        s[t] += v;
        __syncthreads();
    }
    int run = s[t] - sum;  // exclusive prefix of this thread's chunk
    for (int i = lo; i < hi; ++i) {
        int d = degi[i];
        cursor[i] = run;
        dinv[i] = rsqrtf((float)d + 1.0f);
        run += d;
        rowptr[i + 1] = run;
    }
    if (t == 0) rowptr[0] = 0;
}

__global__ void k_fill(const int* __restrict__ src, const int* __restrict__ dst, int e,
                       int* __restrict__ cursor, unsigned short* __restrict__ col) {
    int i = blockIdx.x * blockDim.x + threadIdx.x;
    if (i >= e) return;
    int d = dst[i];
    int pos = atomicAdd(&cursor[d], 1);
    col[pos] = (unsigned short)src[i];
}

// ---------------- all weight transposes in one kernel ----------------
// W1T[m*128+k]=bf16(W1[k*128+m]); W2T[m*128+k]=bf16(W2[k*64+m]); fcWT[m*64+k]=bf16(fcW[k*64+m])
__global__ void k_wt_all(const float* __restrict__ W1, const float* __restrict__ W2,
                         const float* __restrict__ fcW,
                         unsigned short* __restrict__ W1T, unsigned short* __restrict__ W2T,
                         unsigned short* __restrict__ fcWT) {
    int i = blockIdx.x * blockDim.x + threadIdx.x;
    if (i < 16384) {
        int m = i >> 7, k = i & 127;
        W1T[i] = f2bf(W1[k * 128 + m]);
    } else if (i < 24576) {
        int j = i - 16384;
        int m = j >> 7, k = j & 127;
        W2T[j] = f2bf(W2[k * 64 + m]);
    } else if (i < 28672) {
        int j = i - 24576;
        int m = j >> 6, k = j & 63;
        fcWT[j] = f2bf(fcW[k * 64 + m]);
    }
}

// ---------------- MFMA GEMM (layer 1): hs1 = bf16((x@W1)*dinv) ----------------
// Block 256 thr = 4 waves, 64 rows. A-frag from padded LDS (ds_read_b128).
__global__ __launch_bounds__(256) void k_mgemm1(
    const float* __restrict__ X, const unsigned short* __restrict__ WT,
    const float* __restrict__ dinv, unsigned short* __restrict__ out, int n) {
    constexpr int K = 128, M = 128, LDW = K + 8;
    __shared__ __align__(16) unsigned short xs[64 * LDW];
    int tid = threadIdx.x;
    int base = blockIdx.x * 64;

    constexpr int C4 = K / 4;
    for (int idx = tid; idx < 64 * C4; idx += 256) {
        int r = idx / C4, c = idx - r * C4;
        int row = base + r;
        float4 v = make_float4(0.f, 0.f, 0.f, 0.f);
        if (row < n) v = ((const float4*)X)[(size_t)row * C4 + c];
        unsigned short* d = &xs[r * LDW + c * 4];
        d[0] = f2bf(v.x); d[1] = f2bf(v.y); d[2] = f2bf(v.z); d[3] = f2bf(v.w);
    }
    __syncthreads();

    int wave = tid >> 6, lane = tid & 63;
    int quad = lane >> 4, l16 = lane & 15;
    int rbase = wave * 16;

    bf16x8 afrag[4];
#pragma unroll
    for (int kb = 0; kb < 4; ++kb)
        afrag[kb] = *(const bf16x8*)&xs[(rbase + l16) * LDW + kb * 32 + quad * 8];

    float dv[4];
#pragma unroll
    for (int r = 0; r < 4; ++r) {
        int row = base + rbase + quad * 4 + r;
        dv[r] = (row < n) ? dinv[row] : 0.f;
    }

#pragma unroll
    for (int jt = 0; jt < M / 16; ++jt) {
        f32x4 acc = {0.f, 0.f, 0.f, 0.f};
#pragma unroll
        for (int kb = 0; kb < 4; ++kb) {
            bf16x8 bfrag = *(const bf16x8*)&WT[(size_t)(jt * 16 + l16) * K + kb * 32 + quad * 8];
            acc = __builtin_amdgcn_mfma_f32_16x16x32_bf16(afrag[kb], bfrag, acc, 0, 0, 0);
        }
        int colj = jt * 16 + l16;
#pragma unroll
        for (int r = 0; r < 4; ++r) {
            int row = base + rbase + quad * 4 + r;
            if (row < n) out[(size_t)row * M + colj] = f2bf(acc[r] * dv[r]);
        }
    }
}

// ---------------- fused1: CSR-agg(hs1,128) + relu -> LDS -> MFMA @W2 -> bf16 hs2 ----------------
__global__ __launch_bounds__(256) void k_fused1(
    const int* __restrict__ rowptr, const unsigned short* __restrict__ col,
    const unsigned* __restrict__ hs1p,  // packed bf16 pairs, 64/row
    const float* __restrict__ dinv, const float* __restrict__ b1,
    const unsigned short* __restrict__ W2T, unsigned short* __restrict__ hs2, int n) {
    constexpr int K = 128, M = 64, LDW = K + 8;  // LDW*2=272B, 16B-aligned rows
    __shared__ __align__(16) unsigned short xs[64 * LDW];
    int tid = threadIdx.x, wave = tid >> 6, lane = tid & 63;
    int base = blockIdx.x * 64;

    float b1x = b1[2 * lane], b1y = b1[2 * lane + 1];

    for (int r = 0; r < 16; ++r) {
        int node = base + wave * 16 + r;
        unsigned pv = 0;
        if (node < n) {
            int beg = rowptr[node], end = rowptr[node + 1];
            float di = dinv[node];
            unsigned su = hs1p[(size_t)node * 64 + lane];
            float ax0 = bf16_lo(su), ay0 = bf16_hi(su);
            float ax1 = 0.f, ay1 = 0.f, ax2 = 0.f, ay2 = 0.f, ax3 = 0.f, ay3 = 0.f;
            int i = beg;
            for (; i + 3 < end; i += 4) {
                unsigned u0 = hs1p[(size_t)col[i]     * 64 + lane];
                unsigned u1 = hs1p[(size_t)col[i + 1] * 64 + lane];
                unsigned u2 = hs1p[(size_t)col[i + 2] * 64 + lane];
                unsigned u3 = hs1p[(size_t)col[i + 3] * 64 + lane];
                ax0 += bf16_lo(u0); ay0 += bf16_hi(u0);
                ax1 += bf16_lo(u1); ay1 += bf16_hi(u1);
                ax2 += bf16_lo(u2); ay2 += bf16_hi(u2);
                ax3 += bf16_lo(u3); ay3 += bf16_hi(u3);
            }
            for (; i < end; ++i) {
                unsigned u0 = hs1p[(size_t)col[i] * 64 + lane];
                ax0 += bf16_lo(u0); ay0 += bf16_hi(u0);
            }
            float vx = fmaxf(di * ((ax0 + ax1) + (ax2 + ax3)) + b1x, 0.0f);
            float vy = fmaxf(di * ((ay0 + ay1) + (ay2 + ay3)) + b1y, 0.0f);
            pv = (unsigned)f2bf(vx) | ((unsigned)f2bf(vy) << 16);
        }
        *(unsigned*)&xs[(wave * 16 + r) * LDW + 2 * lane] = pv;
    }
    __syncthreads();

    int quad = lane >> 4, l16 = lane & 15;
    int rbase = wave * 16;

    bf16x8 afrag[4];
#pragma unroll
    for (int kb = 0; kb < 4; ++kb)
        afrag[kb] = *(const bf16x8*)&xs[(rbase + l16) * LDW + kb * 32 + quad * 8];

    float dv[4];
#pragma unroll
    for (int r = 0; r < 4; ++r) {
        int row = base + rbase + quad * 4 + r;
        dv[r] = (row < n) ? dinv[row] : 0.f;
    }

#pragma unroll
    for (int jt = 0; jt < M / 16; ++jt) {
        f32x4 acc = {0.f, 0.f, 0.f, 0.f};
#pragma unroll
        for (int kb = 0; kb < 4; ++kb) {
            bf16x8 bfrag = *(const bf16x8*)&W2T[(size_t)(jt * 16 + l16) * K + kb * 32 + quad * 8];
            acc = __builtin_amdgcn_mfma_f32_16x16x32_bf16(afrag[kb], bfrag, acc, 0, 0, 0);
        }
        int colj = jt * 16 + l16;
#pragma unroll
        for (int r = 0; r < 4; ++r) {
            int row = base + rbase + quad * 4 + r;
            if (row < n) hs2[(size_t)row * M + colj] = f2bf(acc[r] * dv[r]);
        }
    }
}

// ---------------- fused2: CSR-agg(hs2,64) + relu -> LDS -> MFMA @fcW + fcb -> fp32 out ----------------
__global__ __launch_bounds__(256) void k_fused2(
    const int* __restrict__ rowptr, const unsigned short* __restrict__ col,
    const unsigned short* __restrict__ hs2, const float* __restrict__ dinv,
    const float* __restrict__ b2, const unsigned short* __restrict__ fcWT,
    const float* __restrict__ fcb, float* __restrict__ out, int n) {
    constexpr int K = 64, M = 64, LDW = K + 8;  // LDW*2=144B, 16B-aligned rows
    __shared__ __align__(16) unsigned short xs[64 * LDW];
    int tid = threadIdx.x, wave = tid >> 6, lane = tid & 63;
    int base = blockIdx.x * 64;

    float b2l = b2[lane];

    for (int r = 0; r < 16; ++r) {
        int node = base + wave * 16 + r;
        unsigned short hv = 0;
        if (node < n) {
            int beg = rowptr[node], end = rowptr[node + 1];
            float di = dinv[node];
            float a0 = bf16_one(hs2[(size_t)node * 64 + lane]);
            float a1 = 0.f, a2 = 0.f, a3 = 0.f;
            int i = beg;
            for (; i + 3 < end; i += 4) {
                a0 += bf16_one(hs2[(size_t)col[i]     * 64 + lane]);
                a1 += bf16_one(hs2[(size_t)col[i + 1] * 64 + lane]);
                a2 += bf16_one(hs2[(size_t)col[i + 2] * 64 + lane]);
                a3 += bf16_one(hs2[(size_t)col[i + 3] * 64 + lane]);
            }
            for (; i < end; ++i) a0 += bf16_one(hs2[(size_t)col[i] * 64 + lane]);
            float v = fmaxf(di * ((a0 + a1) + (a2 + a3)) + b2l, 0.0f);
            hv = f2bf(v);
        }
        xs[(wave * 16 + r) * LDW + lane] = hv;
    }
    __syncthreads();

    int quad = lane >> 4, l16 = lane & 15;
    int rbase = wave * 16;

    bf16x8 afrag[2];
#pragma unroll
    for (int kb = 0; kb < 2; ++kb)
        afrag[kb] = *(const bf16x8*)&xs[(rbase + l16) * LDW + kb * 32 + quad * 8];

#pragma unroll
    for (int jt = 0; jt < M / 16; ++jt) {
        f32x4 acc = {0.f, 0.f, 0.f, 0.f};
#pragma unroll
        for (int kb = 0; kb < 2; ++kb) {
            bf16x8 bfrag = *(const bf16x8*)&fcWT[(size_t)(jt * 16 + l16) * K + kb * 32 + quad * 8];
            acc = __builtin_amdgcn_mfma_f32_16x16x32_bf16(afrag[kb], bfrag, acc, 0, 0, 0);
        }
        int colj = jt * 16 + l16;
        float bv = fcb[colj];
#pragma unroll
        for (int r = 0; r < 4; ++r) {
            int row = base + rbase + quad * 4 + r;
            if (row < n) out[(size_t)row * M + colj] = acc[r] + bv;
        }
    }
}

// ---------------- launch ----------------

extern "C" void kernel_launch(void* const* d_in, const int* in_sizes, int n_in,
                              void* d_out, int out_size, void* d_ws, size_t ws_size,
                              hipStream_t stream) {
    const float* x   = (const float*)d_in[0];
    const int*   ei  = (const int*)d_in[1];
    const float* W1  = (const float*)d_in[2];
    const float* b1  = (const float*)d_in[3];
    const float* W2  = (const float*)d_in[4];
    const float* b2  = (const float*)d_in[5];
    const float* fcW = (const float*)d_in[6];
    const float* fcb = (const float*)d_in[7];
    float* out = (float*)d_out;

    const int N = in_sizes[0] / 128;
    const int E = in_sizes[1] / 2;
    const int* src = ei;
    const int* dst = ei + E;

    // ---- workspace carve (16B-aligned), peak ~22 MB ----
    auto align16 = [](size_t v) { return (v + 15) & ~(size_t)15; };
    char* p = (char*)d_ws;
    int* rowptr = (int*)p;                     p += align16(sizeof(int) * (N + 1));
    unsigned short* col = (unsigned short*)p;  p += align16(sizeof(unsigned short) * E);
    float* dinv = (float*)p;                   p += align16(sizeof(float) * N);
    int* degi = (int*)p;                       p += align16(sizeof(int) * N);
    int* cursor = (int*)p;                     p += align16(sizeof(int) * N);
    unsigned short* W1T = (unsigned short*)p;  p += align16(2 * 128 * 128);
    unsigned short* W2T = (unsigned short*)p;  p += align16(2 * 64 * 128);
    unsigned short* fcWT = (unsigned short*)p; p += align16(2 * 64 * 64);
    unsigned short* hs1 = (unsigned short*)p;  p += align16(2 * (size_t)N * 128);  // bf16
    unsigned short* hs2 = (unsigned short*)p;  p += align16(2 * (size_t)N * 64);   // bf16

    const int B = 256;
    const int gg = (N + 63) / 64;

    hipMemsetAsync(degi, 0, sizeof(int) * N, stream);
    k_count<<<(E + B - 1) / B, B, 0, stream>>>(dst, E, degi);
    k_scan_all<<<1, 1024, 0, stream>>>(degi, rowptr, cursor, dinv, N);
    k_fill<<<(E + B - 1) / B, B, 0, stream>>>(src, dst, E, cursor, col);
    k_wt_all<<<(28672 + B - 1) / B, B, 0, stream>>>(W1, W2, fcW, W1T, W2T, fcWT);

    k_mgemm1<<<gg, 256, 0, stream>>>(x, W1T, dinv, hs1, N);
    k_fused1<<<gg, 256, 0, stream>>>(rowptr, col, (const unsigned*)hs1, dinv, b1, W2T, hs2, N);
    k_fused2<<<gg, 256, 0, stream>>>(rowptr, col, hs2, dinv, b2, fcWT, fcb, out, N);
}

// Round 7
// 289.218 us; speedup vs baseline: 1.5759x; 1.5759x over previous
//
#include <hip/hip_runtime.h>
#include <hip/hip_bf16.h>

// GCN_85804856639970 — 2-layer GCN + FC head, MI355X.
// N=50000, E=800000, 128->128->64, head 64x64. fp32 in/out, edge_index int32.
//
// R7 = R5 structure (proven 294 us) + merged weight transpose + memset degi.
// Key lesson from R6: the CSR gather is LATENCY-bound -> wave-per-node (50k waves)
// beats fused block-gather (3 blocks/CU). Single-block scan was a 133 us disaster.
//   dinv = rsqrt(in_deg+1)
//   hs = (X@W)*dinv[row]   (MFMA GEMM, pre-scale epilogue, bf16 out)
//   h  = relu(dinv*(hs[i]+sum_nbr hs)+b)  (CSR gather, wave per node)
//   out = h2@fcW + fcb     (MFMA GEMM, bias epilogue, fp32 out)

typedef __attribute__((ext_vector_type(8))) short bf16x8;
typedef __attribute__((ext_vector_type(4))) float f32x4;

__device__ __forceinline__ unsigned short f2bf(float f) {
    unsigned u = __float_as_uint(f);
    unsigned r = (u + 0x7FFFu + ((u >> 16) & 1u)) >> 16;
    return (unsigned short)r;
}
__device__ __forceinline__ float bf16_lo(unsigned u) {
    return __uint_as_float((u & 0xFFFFu) << 16);
}
__device__ __forceinline__ float bf16_hi(unsigned u) {
    return __uint_as_float(u & 0xFFFF0000u);
}
__device__ __forceinline__ float bf16_one(unsigned short u) {
    return __uint_as_float(((unsigned)u) << 16);
}

// ---------------- CSR build ----------------

__global__ void k_count(const int* __restrict__ dst, int e, int* __restrict__ degi) {
    int i = blockIdx.x * blockDim.x + threadIdx.x;
    if (i < e) atomicAdd(&degi[dst[i]], 1);
}

__global__ void k_scan1(const int* __restrict__ degi, int* __restrict__ rowptr,
                        int* __restrict__ blocksum, int n) {
    __shared__ int s[256];
    int tid = threadIdx.x;
    int i = blockIdx.x * 256 + tid;
    s[tid] = (i < n) ? degi[i] : 0;
    __syncthreads();
#pragma unroll
    for (int off = 1; off < 256; off <<= 1) {
        int t = (tid >= off) ? s[tid - off] : 0;
        __syncthreads();
        s[tid] += t;
        __syncthreads();
    }
    if (i < n) rowptr[i + 1] = s[tid];
    if (tid == 255) blocksum[blockIdx.x] = s[255];
}

__global__ void k_scan2(int* __restrict__ blocksum, int nb) {
    __shared__ int s[256];
    int tid = threadIdx.x;
    s[tid] = (tid < nb) ? blocksum[tid] : 0;
    __syncthreads();
#pragma unroll
    for (int off = 1; off < 256; off <<= 1) {
        int t = (tid >= off) ? s[tid - off] : 0;
        __syncthreads();
        s[tid] += t;
        __syncthreads();
    }
    if (tid < nb) blocksum[tid] = s[tid];
}

__global__ void k_scan3(int* __restrict__ rowptr, const int* __restrict__ blocksum,
                        const int* __restrict__ degi, int* __restrict__ cursor,
                        float* __restrict__ dinv, int n) {
    int i = blockIdx.x * blockDim.x + threadIdx.x;
    if (i >= n) return;
    int off = (blockIdx.x > 0) ? blocksum[blockIdx.x - 1] : 0;
    int incl = rowptr[i + 1] + off;
    rowptr[i + 1] = incl;
    cursor[i] = incl - degi[i];
    dinv[i] = rsqrtf((float)degi[i] + 1.0f);
    if (i == 0) rowptr[0] = 0;
}

__global__ void k_fill(const int* __restrict__ src, const int* __restrict__ dst, int e,
                       int* __restrict__ cursor, unsigned short* __restrict__ col) {
    int i = blockIdx.x * blockDim.x + threadIdx.x;
    if (i >= e) return;
    int d = dst[i];
    int pos = atomicAdd(&cursor[d], 1);
    col[pos] = (unsigned short)src[i];
}

// ---------------- all weight transposes in one kernel ----------------
__global__ void k_wt_all(const float* __restrict__ W1, const float* __restrict__ W2,
                         const float* __restrict__ fcW,
                         unsigned short* __restrict__ W1T, unsigned short* __restrict__ W2T,
                         unsigned short* __restrict__ fcWT) {
    int i = blockIdx.x * blockDim.x + threadIdx.x;
    if (i < 16384) {
        int m = i >> 7, k = i & 127;
        W1T[i] = f2bf(W1[k * 128 + m]);
    } else if (i < 24576) {
        int j = i - 16384;
        int m = j >> 7, k = j & 127;
        W2T[j] = f2bf(W2[k * 64 + m]);
    } else if (i < 28672) {
        int j = i - 24576;
        int m = j >> 6, k = j & 63;
        fcWT[j] = f2bf(fcW[k * 64 + m]);
    }
}

// ---------------- MFMA GEMM ----------------
// C[n x M] = X[n x K] @ W[K x M], W as WT[M][K] bf16. 256 thr = 4 waves, 64 rows/block.
// MODE 0: store bf16(acc*dinv[row]).  MODE 1: store fp32(acc + bias[col]).
template <int K, int M, int MODE, typename TIN>
__global__ __launch_bounds__(256) void k_mgemm(
    const TIN* __restrict__ X, const unsigned short* __restrict__ WT,
    const float* __restrict__ dinv, const float* __restrict__ bias,
    void* __restrict__ outv, int n) {
    constexpr int LDW = K + 8;
    __shared__ __align__(16) unsigned short xs[64 * LDW];
    int tid = threadIdx.x;
    int base = blockIdx.x * 64;

    if constexpr (sizeof(TIN) == 4) {  // fp32 -> bf16 convert while staging
        constexpr int C4 = K / 4;
        for (int idx = tid; idx < 64 * C4; idx += 256) {
            int r = idx / C4, c = idx - r * C4;
            int row = base + r;
            float4 v = make_float4(0.f, 0.f, 0.f, 0.f);
            if (row < n) v = ((const float4*)X)[(size_t)row * C4 + c];
            unsigned short* d = &xs[r * LDW + c * 4];
            d[0] = f2bf(v.x); d[1] = f2bf(v.y); d[2] = f2bf(v.z); d[3] = f2bf(v.w);
        }
    } else {  // bf16 input, 16B copies
        constexpr int C8 = K / 8;
        for (int idx = tid; idx < 64 * C8; idx += 256) {
            int r = idx / C8, c = idx - r * C8;
            int row = base + r;
            uint4 v = make_uint4(0u, 0u, 0u, 0u);
            if (row < n) v = ((const uint4*)X)[(size_t)row * C8 + c];
            *(uint4*)&xs[r * LDW + c * 8] = v;
        }
    }
    __syncthreads();

    int wave = tid >> 6, lane = tid & 63;
    int quad = lane >> 4, l16 = lane & 15;
    int rbase = wave * 16;
    constexpr int KB = K / 32;

    bf16x8 afrag[KB];
#pragma unroll
    for (int kb = 0; kb < KB; ++kb)
        afrag[kb] = *(const bf16x8*)&xs[(rbase + l16) * LDW + kb * 32 + quad * 8];

    float dv[4];
#pragma unroll
    for (int r = 0; r < 4; ++r) {
        int row = base + rbase + quad * 4 + r;
        dv[r] = (MODE == 0 && row < n) ? dinv[row] : 0.f;
    }

#pragma unroll
    for (int jt = 0; jt < M / 16; ++jt) {
        f32x4 acc = {0.f, 0.f, 0.f, 0.f};
#pragma unroll
        for (int kb = 0; kb < KB; ++kb) {
            bf16x8 bfrag = *(const bf16x8*)&WT[(size_t)(jt * 16 + l16) * K + kb * 32 + quad * 8];
            acc = __builtin_amdgcn_mfma_f32_16x16x32_bf16(afrag[kb], bfrag, acc, 0, 0, 0);
        }
        int colj = jt * 16 + l16;
        float bv = (MODE == 1) ? bias[colj] : 0.f;
#pragma unroll
        for (int r = 0; r < 4; ++r) {
            int row = base + rbase + quad * 4 + r;
            if (row < n) {
                if constexpr (MODE == 0)
                    ((unsigned short*)outv)[(size_t)row * M + colj] = f2bf(acc[r] * dv[r]);
                else
                    ((float*)outv)[(size_t)row * M + colj] = acc[r] + bv;
            }
        }
    }
}

// ---------------- CSR aggregation (wave per node), bf16 hs ----------------
template <int M>
__global__ void k_agg(const int* __restrict__ rowptr, const unsigned short* __restrict__ col,
                      const unsigned short* __restrict__ hs, const float* __restrict__ dinv,
                      const float* __restrict__ bias, unsigned short* __restrict__ out, int n) {
    int wave = threadIdx.x >> 6;
    int lane = threadIdx.x & 63;
    int node = blockIdx.x * 4 + wave;
    if (node >= n) return;

    int beg = rowptr[node];
    int end = rowptr[node + 1];
    float di = dinv[node];

    if constexpr (M == 128) {
        const unsigned* hp = (const unsigned*)hs;  // row = 64 packed bf16 pairs
        unsigned su = hp[(size_t)node * 64 + lane];
        float ax0 = bf16_lo(su), ay0 = bf16_hi(su);
        float ax1 = 0.f, ay1 = 0.f, ax2 = 0.f, ay2 = 0.f, ax3 = 0.f, ay3 = 0.f;
        int i = beg;
        for (; i + 3 < end; i += 4) {
            unsigned u0 = hp[(size_t)col[i]     * 64 + lane];
            unsigned u1 = hp[(size_t)col[i + 1] * 64 + lane];
            unsigned u2 = hp[(size_t)col[i + 2] * 64 + lane];
            unsigned u3 = hp[(size_t)col[i + 3] * 64 + lane];
            ax0 += bf16_lo(u0); ay0 += bf16_hi(u0);
            ax1 += bf16_lo(u1); ay1 += bf16_hi(u1);
            ax2 += bf16_lo(u2); ay2 += bf16_hi(u2);
            ax3 += bf16_lo(u3); ay3 += bf16_hi(u3);
        }
        for (; i < end; ++i) {
            unsigned u0 = hp[(size_t)col[i] * 64 + lane];
            ax0 += bf16_lo(u0); ay0 += bf16_hi(u0);
        }
        float vx = fmaxf(di * ((ax0 + ax1) + (ax2 + ax3)) + bias[2 * lane], 0.0f);
        float vy = fmaxf(di * ((ay0 + ay1) + (ay2 + ay3)) + bias[2 * lane + 1], 0.0f);
        ((unsigned*)out)[(size_t)node * 64 + lane] =
            (unsigned)f2bf(vx) | ((unsigned)f2bf(vy) << 16);
    } else {  // M == 64
        float a0 = bf16_one(hs[(size_t)node * 64 + lane]);
        float a1 = 0.f, a2 = 0.f, a3 = 0.f;
        int i = beg;
        for (; i + 3 < end; i += 4) {
            a0 += bf16_one(hs[(size_t)col[i]     * 64 + lane]);
            a1 += bf16_one(hs[(size_t)col[i + 1] * 64 + lane]);
            a2 += bf16_one(hs[(size_t)col[i + 2] * 64 + lane]);
            a3 += bf16_one(hs[(size_t)col[i + 3] * 64 + lane]);
        }
        for (; i < end; ++i) a0 += bf16_one(hs[(size_t)col[i] * 64 + lane]);
        float v = fmaxf(di * ((a0 + a1) + (a2 + a3)) + bias[lane], 0.0f);
        out[(size_t)node * 64 + lane] = f2bf(v);
    }
}

// ---------------- launch ----------------

extern "C" void kernel_launch(void* const* d_in, const int* in_sizes, int n_in,
                              void* d_out, int out_size, void* d_ws, size_t ws_size,
                              hipStream_t stream) {
    const float* x   = (const float*)d_in[0];
    const int*   ei  = (const int*)d_in[1];
    const float* W1  = (const float*)d_in[2];
    const float* b1  = (const float*)d_in[3];
    const float* W2  = (const float*)d_in[4];
    const float* b2  = (const float*)d_in[5];
    const float* fcW = (const float*)d_in[6];
    const float* fcb = (const float*)d_in[7];
    float* out = (float*)d_out;

    const int N = in_sizes[0] / 128;
    const int E = in_sizes[1] / 2;
    const int* src = ei;
    const int* dst = ei + E;

    // ---- workspace carve (16B-aligned), peak ~22 MB ----
    auto align16 = [](size_t v) { return (v + 15) & ~(size_t)15; };
    char* p = (char*)d_ws;
    int* rowptr = (int*)p;                     p += align16(sizeof(int) * (N + 1));
    unsigned short* col = (unsigned short*)p;  p += align16(sizeof(unsigned short) * E);
    float* dinv = (float*)p;                   p += align16(sizeof(float) * N);
    int* degi = (int*)p;                       p += align16(sizeof(int) * N);
    int* cursor = (int*)p;                     p += align16(sizeof(int) * N);
    int* blocksum = (int*)p;                   p += align16(sizeof(int) * 256);
    unsigned short* W1T = (unsigned short*)p;  p += align16(2 * 128 * 128);
    unsigned short* W2T = (unsigned short*)p;  p += align16(2 * 64 * 128);
    unsigned short* fcWT = (unsigned short*)p; p += align16(2 * 64 * 64);
    unsigned short* hs1 = (unsigned short*)p;  p += align16(2 * (size_t)N * 128);
    unsigned short* h1  = (unsigned short*)p;  p += align16(2 * (size_t)N * 128);
    unsigned short* hs2 = (unsigned short*)p;  p += align16(2 * (size_t)N * 64);
    unsigned short* h2  = (unsigned short*)p;  p += align16(2 * (size_t)N * 64);

    const int B = 256;
    const int nb = (N + 255) / 256;
    const int gg = (N + 63) / 64;

    // CSR build (multi-block scan — R6's single-block scan was a 133 us serial trap)
    hipMemsetAsync(degi, 0, sizeof(int) * N, stream);
    k_count<<<(E + B - 1) / B, B, 0, stream>>>(dst, E, degi);
    k_scan1<<<nb, 256, 0, stream>>>(degi, rowptr, blocksum, N);
    k_scan2<<<1, 256, 0, stream>>>(blocksum, nb);
    k_scan3<<<nb, 256, 0, stream>>>(rowptr, blocksum, degi, cursor, dinv, N);
    k_fill<<<(E + B - 1) / B, B, 0, stream>>>(src, dst, E, cursor, col);
    k_wt_all<<<(28672 + B - 1) / B, B, 0, stream>>>(W1, W2, fcW, W1T, W2T, fcWT);

    // Layer 1: 128 -> 128
    k_mgemm<128, 128, 0, float><<<gg, 256, 0, stream>>>(x, W1T, dinv, nullptr, hs1, N);
    k_agg<128><<<(N + 3) / 4, 256, 0, stream>>>(rowptr, col, hs1, dinv, b1, h1, N);

    // Layer 2: 128 -> 64
    k_mgemm<128, 64, 0, unsigned short><<<gg, 256, 0, stream>>>(h1, W2T, dinv, nullptr, hs2, N);
    k_agg<64><<<(N + 3) / 4, 256, 0, stream>>>(rowptr, col, hs2, dinv, b2, h2, N);

    // FC head: 64 -> 64, fp32 out
    k_mgemm<64, 64, 1, unsigned short><<<gg, 256, 0, stream>>>(h2, fcWT, nullptr, fcb, out, N);
}

// Round 8
// 278.759 us; speedup vs baseline: 1.6350x; 1.0375x over previous
//
#include <hip/hip_runtime.h>
#include <hip/hip_bf16.h>

// GCN_85804856639970 — 2-layer GCN + FC head, MI355X.
// N=50000, E=800000, 128->128->64, head 64x64. fp32 in/out, edge_index int32.
//
// R8 = R7 (289 us) + deeper gather ILP (8 outstanding) + int4 edge reads
//      + weight-transpose merged into the count dispatch (12 -> 11 launches).
// Lessons kept: wave-per-node gather (TLP), multi-block scan, MFMA GEMMs.

typedef __attribute__((ext_vector_type(8))) short bf16x8;
typedef __attribute__((ext_vector_type(4))) float f32x4;

__device__ __forceinline__ unsigned short f2bf(float f) {
    unsigned u = __float_as_uint(f);
    unsigned r = (u + 0x7FFFu + ((u >> 16) & 1u)) >> 16;
    return (unsigned short)r;
}
__device__ __forceinline__ float bf16_lo(unsigned u) {
    return __uint_as_float((u & 0xFFFFu) << 16);
}
__device__ __forceinline__ float bf16_hi(unsigned u) {
    return __uint_as_float(u & 0xFFFF0000u);
}
__device__ __forceinline__ float bf16_one(unsigned short u) {
    return __uint_as_float(((unsigned)u) << 16);
}

// ---------------- count (4 edges/thread, int4) + weight transpose, one dispatch ----------------

__global__ void k_count_wt(const int* __restrict__ dst, int e, int* __restrict__ degi,
                           const float* __restrict__ W1, const float* __restrict__ W2,
                           const float* __restrict__ fcW,
                           unsigned short* __restrict__ W1T, unsigned short* __restrict__ W2T,
                           unsigned short* __restrict__ fcWT, int cntBlocks) {
    if ((int)blockIdx.x < cntBlocks) {
        int t = blockIdx.x * blockDim.x + threadIdx.x;
        int b = t * 4;
        if (b + 3 < e) {
            int4 d4 = *(const int4*)&dst[b];
            atomicAdd(&degi[d4.x], 1);
            atomicAdd(&degi[d4.y], 1);
            atomicAdd(&degi[d4.z], 1);
            atomicAdd(&degi[d4.w], 1);
        } else {
            for (int i = b; i < e; ++i) atomicAdd(&degi[dst[i]], 1);
        }
    } else {
        int j = ((int)blockIdx.x - cntBlocks) * blockDim.x + threadIdx.x;
        if (j < 16384) {
            int m = j >> 7, k = j & 127;
            W1T[j] = f2bf(W1[k * 128 + m]);
        } else if (j < 24576) {
            int q = j - 16384;
            int m = q >> 7, k = q & 127;
            W2T[q] = f2bf(W2[k * 64 + m]);
        } else if (j < 28672) {
            int q = j - 24576;
            int m = q >> 6, k = q & 63;
            fcWT[q] = f2bf(fcW[k * 64 + m]);
        }
    }
}

// ---------------- multi-block scan ----------------

__global__ void k_scan1(const int* __restrict__ degi, int* __restrict__ rowptr,
                        int* __restrict__ blocksum, int n) {
    __shared__ int s[256];
    int tid = threadIdx.x;
    int i = blockIdx.x * 256 + tid;
    s[tid] = (i < n) ? degi[i] : 0;
    __syncthreads();
#pragma unroll
    for (int off = 1; off < 256; off <<= 1) {
        int t = (tid >= off) ? s[tid - off] : 0;
        __syncthreads();
        s[tid] += t;
        __syncthreads();
    }
    if (i < n) rowptr[i + 1] = s[tid];
    if (tid == 255) blocksum[blockIdx.x] = s[255];
}

__global__ void k_scan2(int* __restrict__ blocksum, int nb) {
    __shared__ int s[256];
    int tid = threadIdx.x;
    s[tid] = (tid < nb) ? blocksum[tid] : 0;
    __syncthreads();
#pragma unroll
    for (int off = 1; off < 256; off <<= 1) {
        int t = (tid >= off) ? s[tid - off] : 0;
        __syncthreads();
        s[tid] += t;
        __syncthreads();
    }
    if (tid < nb) blocksum[tid] = s[tid];
}

__global__ void k_scan3(int* __restrict__ rowptr, const int* __restrict__ blocksum,
                        const int* __restrict__ degi, int* __restrict__ cursor,
                        float* __restrict__ dinv, int n) {
    int i = blockIdx.x * blockDim.x + threadIdx.x;
    if (i >= n) return;
    int off = (blockIdx.x > 0) ? blocksum[blockIdx.x - 1] : 0;
    int incl = rowptr[i + 1] + off;
    rowptr[i + 1] = incl;
    cursor[i] = incl - degi[i];
    dinv[i] = rsqrtf((float)degi[i] + 1.0f);
    if (i == 0) rowptr[0] = 0;
}

// ---------------- fill (4 edges/thread, int4) ----------------

__global__ void k_fill(const int* __restrict__ src, const int* __restrict__ dst, int e,
                       int* __restrict__ cursor, unsigned short* __restrict__ col) {
    int t = blockIdx.x * blockDim.x + threadIdx.x;
    int b = t * 4;
    if (b + 3 < e) {
        int4 s4 = *(const int4*)&src[b];
        int4 d4 = *(const int4*)&dst[b];
        col[atomicAdd(&cursor[d4.x], 1)] = (unsigned short)s4.x;
        col[atomicAdd(&cursor[d4.y], 1)] = (unsigned short)s4.y;
        col[atomicAdd(&cursor[d4.z], 1)] = (unsigned short)s4.z;
        col[atomicAdd(&cursor[d4.w], 1)] = (unsigned short)s4.w;
    } else {
        for (int i = b; i < e; ++i)
            col[atomicAdd(&cursor[dst[i]], 1)] = (unsigned short)src[i];
    }
}

// ---------------- MFMA GEMM ----------------
// C[n x M] = X[n x K] @ W[K x M], W as WT[M][K] bf16. 256 thr = 4 waves, 64 rows/block.
// MODE 0: store bf16(acc*dinv[row]).  MODE 1: store fp32(acc + bias[col]).
template <int K, int M, int MODE, typename TIN>
__global__ __launch_bounds__(256) void k_mgemm(
    const TIN* __restrict__ X, const unsigned short* __restrict__ WT,
    const float* __restrict__ dinv, const float* __restrict__ bias,
    void* __restrict__ outv, int n) {
    constexpr int LDW = K + 8;
    __shared__ __align__(16) unsigned short xs[64 * LDW];
    int tid = threadIdx.x;
    int base = blockIdx.x * 64;

    if constexpr (sizeof(TIN) == 4) {
        constexpr int C4 = K / 4;
        for (int idx = tid; idx < 64 * C4; idx += 256) {
            int r = idx / C4, c = idx - r * C4;
            int row = base + r;
            float4 v = make_float4(0.f, 0.f, 0.f, 0.f);
            if (row < n) v = ((const float4*)X)[(size_t)row * C4 + c];
            unsigned short* d = &xs[r * LDW + c * 4];
            d[0] = f2bf(v.x); d[1] = f2bf(v.y); d[2] = f2bf(v.z); d[3] = f2bf(v.w);
        }
    } else {
        constexpr int C8 = K / 8;
        for (int idx = tid; idx < 64 * C8; idx += 256) {
            int r = idx / C8, c = idx - r * C8;
            int row = base + r;
            uint4 v = make_uint4(0u, 0u, 0u, 0u);
            if (row < n) v = ((const uint4*)X)[(size_t)row * C8 + c];
            *(uint4*)&xs[r * LDW + c * 8] = v;
        }
    }
    __syncthreads();

    int wave = tid >> 6, lane = tid & 63;
    int quad = lane >> 4, l16 = lane & 15;
    int rbase = wave * 16;
    constexpr int KB = K / 32;

    bf16x8 afrag[KB];
#pragma unroll
    for (int kb = 0; kb < KB; ++kb)
        afrag[kb] = *(const bf16x8*)&xs[(rbase + l16) * LDW + kb * 32 + quad * 8];

    float dv[4];
#pragma unroll
    for (int r = 0; r < 4; ++r) {
        int row = base + rbase + quad * 4 + r;
        dv[r] = (MODE == 0 && row < n) ? dinv[row] : 0.f;
    }

#pragma unroll
    for (int jt = 0; jt < M / 16; ++jt) {
        f32x4 acc = {0.f, 0.f, 0.f, 0.f};
#pragma unroll
        for (int kb = 0; kb < KB; ++kb) {
            bf16x8 bfrag = *(const bf16x8*)&WT[(size_t)(jt * 16 + l16) * K + kb * 32 + quad * 8];
            acc = __builtin_amdgcn_mfma_f32_16x16x32_bf16(afrag[kb], bfrag, acc, 0, 0, 0);
        }
        int colj = jt * 16 + l16;
        float bv = (MODE == 1) ? bias[colj] : 0.f;
#pragma unroll
        for (int r = 0; r < 4; ++r) {
            int row = base + rbase + quad * 4 + r;
            if (row < n) {
                if constexpr (MODE == 0)
                    ((unsigned short*)outv)[(size_t)row * M + colj] = f2bf(acc[r] * dv[r]);
                else
                    ((float*)outv)[(size_t)row * M + colj] = acc[r] + bv;
            }
        }
    }
}

// ---------------- CSR aggregation (wave per node, 8-deep MLP), bf16 hs ----------------
template <int M>
__global__ void k_agg(const int* __restrict__ rowptr, const unsigned short* __restrict__ col,
                      const unsigned short* __restrict__ hs, const float* __restrict__ dinv,
                      const float* __restrict__ bias, unsigned short* __restrict__ out, int n) {
    int wave = threadIdx.x >> 6;
    int lane = threadIdx.x & 63;
    int node = blockIdx.x * 4 + wave;
    if (node >= n) return;

    int beg = rowptr[node];
    int end = rowptr[node + 1];
    float di = dinv[node];

    if constexpr (M == 128) {
        const unsigned* hp = (const unsigned*)hs;  // row = 64 packed bf16 pairs
        unsigned su = hp[(size_t)node * 64 + lane];
        float ax0 = bf16_lo(su), ay0 = bf16_hi(su);
        float ax1 = 0.f, ay1 = 0.f, ax2 = 0.f, ay2 = 0.f, ax3 = 0.f, ay3 = 0.f;
        int i = beg;
        for (; i + 7 < end; i += 8) {  // 8 outstanding gathers
            unsigned u0 = hp[(size_t)col[i]     * 64 + lane];
            unsigned u1 = hp[(size_t)col[i + 1] * 64 + lane];
            unsigned u2 = hp[(size_t)col[i + 2] * 64 + lane];
            unsigned u3 = hp[(size_t)col[i + 3] * 64 + lane];
            unsigned u4 = hp[(size_t)col[i + 4] * 64 + lane];
            unsigned u5 = hp[(size_t)col[i + 5] * 64 + lane];
            unsigned u6 = hp[(size_t)col[i + 6] * 64 + lane];
            unsigned u7 = hp[(size_t)col[i + 7] * 64 + lane];
            ax0 += bf16_lo(u0); ay0 += bf16_hi(u0);
            ax1 += bf16_lo(u1); ay1 += bf16_hi(u1);
            ax2 += bf16_lo(u2); ay2 += bf16_hi(u2);
            ax3 += bf16_lo(u3); ay3 += bf16_hi(u3);
            ax0 += bf16_lo(u4); ay0 += bf16_hi(u4);
            ax1 += bf16_lo(u5); ay1 += bf16_hi(u5);
            ax2 += bf16_lo(u6); ay2 += bf16_hi(u6);
            ax3 += bf16_lo(u7); ay3 += bf16_hi(u7);
        }
        for (; i + 3 < end; i += 4) {
            unsigned u0 = hp[(size_t)col[i]     * 64 + lane];
            unsigned u1 = hp[(size_t)col[i + 1] * 64 + lane];
            unsigned u2 = hp[(size_t)col[i + 2] * 64 + lane];
            unsigned u3 = hp[(size_t)col[i + 3] * 64 + lane];
            ax0 += bf16_lo(u0); ay0 += bf16_hi(u0);
            ax1 += bf16_lo(u1); ay1 += bf16_hi(u1);
            ax2 += bf16_lo(u2); ay2 += bf16_hi(u2);
            ax3 += bf16_lo(u3); ay3 += bf16_hi(u3);
        }
        for (; i < end; ++i) {
            unsigned u0 = hp[(size_t)col[i] * 64 + lane];
            ax0 += bf16_lo(u0); ay0 += bf16_hi(u0);
        }
        float vx = fmaxf(di * ((ax0 + ax1) + (ax2 + ax3)) + bias[2 * lane], 0.0f);
        float vy = fmaxf(di * ((ay0 + ay1) + (ay2 + ay3)) + bias[2 * lane + 1], 0.0f);
        ((unsigned*)out)[(size_t)node * 64 + lane] =
            (unsigned)f2bf(vx) | ((unsigned)f2bf(vy) << 16);
    } else {  // M == 64
        float a0 = bf16_one(hs[(size_t)node * 64 + lane]);
        float a1 = 0.f, a2 = 0.f, a3 = 0.f;
        float a4 = 0.f, a5 = 0.f, a6 = 0.f, a7 = 0.f;
        int i = beg;
        for (; i + 7 < end; i += 8) {
            a0 += bf16_one(hs[(size_t)col[i]     * 64 + lane]);
            a1 += bf16_one(hs[(size_t)col[i + 1] * 64 + lane]);
            a2 += bf16_one(hs[(size_t)col[i + 2] * 64 + lane]);
            a3 += bf16_one(hs[(size_t)col[i + 3] * 64 + lane]);
            a4 += bf16_one(hs[(size_t)col[i + 4] * 64 + lane]);
            a5 += bf16_one(hs[(size_t)col[i + 5] * 64 + lane]);
            a6 += bf16_one(hs[(size_t)col[i + 6] * 64 + lane]);
            a7 += bf16_one(hs[(size_t)col[i + 7] * 64 + lane]);
        }
        for (; i + 3 < end; i += 4) {
            a0 += bf16_one(hs[(size_t)col[i]     * 64 + lane]);
            a1 += bf16_one(hs[(size_t)col[i + 1] * 64 + lane]);
            a2 += bf16_one(hs[(size_t)col[i + 2] * 64 + lane]);
            a3 += bf16_one(hs[(size_t)col[i + 3] * 64 + lane]);
        }
        for (; i < end; ++i) a0 += bf16_one(hs[(size_t)col[i] * 64 + lane]);
        float v = fmaxf(di * (((a0 + a1) + (a2 + a3)) + ((a4 + a5) + (a6 + a7))) + bias[lane], 0.0f);
        out[(size_t)node * 64 + lane] = f2bf(v);
    }
}

// ---------------- launch ----------------

extern "C" void kernel_launch(void* const* d_in, const int* in_sizes, int n_in,
                              void* d_out, int out_size, void* d_ws, size_t ws_size,
                              hipStream_t stream) {
    const float* x   = (const float*)d_in[0];
    const int*   ei  = (const int*)d_in[1];
    const float* W1  = (const float*)d_in[2];
    const float* b1  = (const float*)d_in[3];
    const float* W2  = (const float*)d_in[4];
    const float* b2  = (const float*)d_in[5];
    const float* fcW = (const float*)d_in[6];
    const float* fcb = (const float*)d_in[7];
    float* out = (float*)d_out;

    const int N = in_sizes[0] / 128;
    const int E = in_sizes[1] / 2;
    const int* src = ei;
    const int* dst = ei + E;

    // ---- workspace carve (16B-aligned), peak ~22 MB ----
    auto align16 = [](size_t v) { return (v + 15) & ~(size_t)15; };
    char* p = (char*)d_ws;
    int* rowptr = (int*)p;                     p += align16(sizeof(int) * (N + 1));
    unsigned short* col = (unsigned short*)p;  p += align16(sizeof(unsigned short) * E);
    float* dinv = (float*)p;                   p += align16(sizeof(float) * N);
    int* degi = (int*)p;                       p += align16(sizeof(int) * N);
    int* cursor = (int*)p;                     p += align16(sizeof(int) * N);
    int* blocksum = (int*)p;                   p += align16(sizeof(int) * 256);
    unsigned short* W1T = (unsigned short*)p;  p += align16(2 * 128 * 128);
    unsigned short* W2T = (unsigned short*)p;  p += align16(2 * 64 * 128);
    unsigned short* fcWT = (unsigned short*)p; p += align16(2 * 64 * 64);
    unsigned short* hs1 = (unsigned short*)p;  p += align16(2 * (size_t)N * 128);
    unsigned short* h1  = (unsigned short*)p;  p += align16(2 * (size_t)N * 128);
    unsigned short* hs2 = (unsigned short*)p;  p += align16(2 * (size_t)N * 64);
    unsigned short* h2  = (unsigned short*)p;  p += align16(2 * (size_t)N * 64);

    const int B = 256;
    const int nb = (N + 255) / 256;
    const int gg = (N + 63) / 64;
    const int cntBlocks = (E + 4 * B - 1) / (4 * B);
    const int wtBlocks = (28672 + B - 1) / B;

    hipMemsetAsync(degi, 0, sizeof(int) * N, stream);
    k_count_wt<<<cntBlocks + wtBlocks, B, 0, stream>>>(dst, E, degi, W1, W2, fcW,
                                                       W1T, W2T, fcWT, cntBlocks);
    k_scan1<<<nb, 256, 0, stream>>>(degi, rowptr, blocksum, N);
    k_scan2<<<1, 256, 0, stream>>>(blocksum, nb);
    k_scan3<<<nb, 256, 0, stream>>>(rowptr, blocksum, degi, cursor, dinv, N);
    k_fill<<<(E + 4 * B - 1) / (4 * B), B, 0, stream>>>(src, dst, E, cursor, col);

    // Layer 1: 128 -> 128
    k_mgemm<128, 128, 0, float><<<gg, 256, 0, stream>>>(x, W1T, dinv, nullptr, hs1, N);
    k_agg<128><<<(N + 3) / 4, 256, 0, stream>>>(rowptr, col, hs1, dinv, b1, h1, N);

    // Layer 2: 128 -> 64
    k_mgemm<128, 64, 0, unsigned short><<<gg, 256, 0, stream>>>(h1, W2T, dinv, nullptr, hs2, N);
    k_agg<64><<<(N + 3) / 4, 256, 0, stream>>>(rowptr, col, hs2, dinv, b2, h2, N);

    // FC head: 64 -> 64, fp32 out
    k_mgemm<64, 64, 1, unsigned short><<<gg, 256, 0, stream>>>(h2, fcWT, nullptr, fcb, out, N);
}

// Round 9
// 277.137 us; speedup vs baseline: 1.6446x; 1.0059x over previous
//
#include <hip/hip_runtime.h>
#include <hip/hip_bf16.h>

// GCN_85804856639970 — 2-layer GCN + FC head, MI355X.
// N=50000, E=800000, 128->128->64, head 64x64. fp32 in/out, edge_index int32.
//
// R9 = R8 (279 us) with:
//  - count & fill back to 1 edge/thread (R8's 4-edge batching cut TLP on a
//    latency-bound kernel: k_fill 46 us @ 25% occupancy, 0.26% VALUBusy)
//  - fill and mgemm1 fused into ONE dispatch via block-range split (they are
//    mutually independent, both depend only on scan3; latency-bound fill
//    co-resides with compute-bound GEMM)
// Lessons kept: wave-per-node gather (TLP), 8-deep gather ILP, multi-block scan,
// MFMA GEMMs with pre-transposed bf16 weights.

typedef __attribute__((ext_vector_type(8))) short bf16x8;
typedef __attribute__((ext_vector_type(4))) float f32x4;

__device__ __forceinline__ unsigned short f2bf(float f) {
    unsigned u = __float_as_uint(f);
    unsigned r = (u + 0x7FFFu + ((u >> 16) & 1u)) >> 16;
    return (unsigned short)r;
}
__device__ __forceinline__ float bf16_lo(unsigned u) {
    return __uint_as_float((u & 0xFFFFu) << 16);
}
__device__ __forceinline__ float bf16_hi(unsigned u) {
    return __uint_as_float(u & 0xFFFF0000u);
}
__device__ __forceinline__ float bf16_one(unsigned short u) {
    return __uint_as_float(((unsigned)u) << 16);
}

// ---------------- count (1 edge/thread) + weight transpose, one dispatch ----------------

__global__ void k_count_wt(const int* __restrict__ dst, int e, int* __restrict__ degi,
                           const float* __restrict__ W1, const float* __restrict__ W2,
                           const float* __restrict__ fcW,
                           unsigned short* __restrict__ W1T, unsigned short* __restrict__ W2T,
                           unsigned short* __restrict__ fcWT, int cntBlocks) {
    if ((int)blockIdx.x < cntBlocks) {
        int i = blockIdx.x * blockDim.x + threadIdx.x;
        if (i < e) atomicAdd(&degi[dst[i]], 1);
    } else {
        int j = ((int)blockIdx.x - cntBlocks) * blockDim.x + threadIdx.x;
        if (j < 16384) {
            int m = j >> 7, k = j & 127;
            W1T[j] = f2bf(W1[k * 128 + m]);
        } else if (j < 24576) {
            int q = j - 16384;
            int m = q >> 7, k = q & 127;
            W2T[q] = f2bf(W2[k * 64 + m]);
        } else if (j < 28672) {
            int q = j - 24576;
            int m = q >> 6, k = q & 63;
            fcWT[q] = f2bf(fcW[k * 64 + m]);
        }
    }
}

// ---------------- multi-block scan ----------------

__global__ void k_scan1(const int* __restrict__ degi, int* __restrict__ rowptr,
                        int* __restrict__ blocksum, int n) {
    __shared__ int s[256];
    int tid = threadIdx.x;
    int i = blockIdx.x * 256 + tid;
    s[tid] = (i < n) ? degi[i] : 0;
    __syncthreads();
#pragma unroll
    for (int off = 1; off < 256; off <<= 1) {
        int t = (tid >= off) ? s[tid - off] : 0;
        __syncthreads();
        s[tid] += t;
        __syncthreads();
    }
    if (i < n) rowptr[i + 1] = s[tid];
    if (tid == 255) blocksum[blockIdx.x] = s[255];
}

__global__ void k_scan2(int* __restrict__ blocksum, int nb) {
    __shared__ int s[256];
    int tid = threadIdx.x;
    s[tid] = (tid < nb) ? blocksum[tid] : 0;
    __syncthreads();
#pragma unroll
    for (int off = 1; off < 256; off <<= 1) {
        int t = (tid >= off) ? s[tid - off] : 0;
        __syncthreads();
        s[tid] += t;
        __syncthreads();
    }
    if (tid < nb) blocksum[tid] = s[tid];
}

__global__ void k_scan3(int* __restrict__ rowptr, const int* __restrict__ blocksum,
                        const int* __restrict__ degi, int* __restrict__ cursor,
                        float* __restrict__ dinv, int n) {
    int i = blockIdx.x * blockDim.x + threadIdx.x;
    if (i >= n) return;
    int off = (blockIdx.x > 0) ? blocksum[blockIdx.x - 1] : 0;
    int incl = rowptr[i + 1] + off;
    rowptr[i + 1] = incl;
    cursor[i] = incl - degi[i];
    dinv[i] = rsqrtf((float)degi[i] + 1.0f);
    if (i == 0) rowptr[0] = 0;
}

// ---------------- fused: fill (1 edge/thread) + mgemm1, one dispatch ----------------
// Blocks [0, fillBlocks): CSR fill. Blocks [fillBlocks, fillBlocks+gg): layer-1 MFMA GEMM.
// Both depend only on scan3 outputs (cursor / dinv) and are independent of each other.

__global__ __launch_bounds__(256) void k_fill_mg1(
    const int* __restrict__ src, const int* __restrict__ dst, int e,
    int* __restrict__ cursor, unsigned short* __restrict__ col,
    const float* __restrict__ X, const unsigned short* __restrict__ WT,
    const float* __restrict__ dinv, unsigned short* __restrict__ out,
    int n, int fillBlocks) {
    constexpr int K = 128, M = 128, LDW = K + 8;
    __shared__ __align__(16) unsigned short xs[64 * LDW];

    if ((int)blockIdx.x < fillBlocks) {
        int i = blockIdx.x * blockDim.x + threadIdx.x;
        if (i < e) {
            int d = dst[i];
            int pos = atomicAdd(&cursor[d], 1);
            col[pos] = (unsigned short)src[i];
        }
        return;
    }

    int bid = (int)blockIdx.x - fillBlocks;
    int tid = threadIdx.x;
    int base = bid * 64;

    constexpr int C4 = K / 4;
    for (int idx = tid; idx < 64 * C4; idx += 256) {
        int r = idx / C4, c = idx - r * C4;
        int row = base + r;
        float4 v = make_float4(0.f, 0.f, 0.f, 0.f);
        if (row < n) v = ((const float4*)X)[(size_t)row * C4 + c];
        unsigned short* d = &xs[r * LDW + c * 4];
        d[0] = f2bf(v.x); d[1] = f2bf(v.y); d[2] = f2bf(v.z); d[3] = f2bf(v.w);
    }
    __syncthreads();

    int wave = tid >> 6, lane = tid & 63;
    int quad = lane >> 4, l16 = lane & 15;
    int rbase = wave * 16;

    bf16x8 afrag[4];
#pragma unroll
    for (int kb = 0; kb < 4; ++kb)
        afrag[kb] = *(const bf16x8*)&xs[(rbase + l16) * LDW + kb * 32 + quad * 8];

    float dv[4];
#pragma unroll
    for (int r = 0; r < 4; ++r) {
        int row = base + rbase + quad * 4 + r;
        dv[r] = (row < n) ? dinv[row] : 0.f;
    }

#pragma unroll
    for (int jt = 0; jt < M / 16; ++jt) {
        f32x4 acc = {0.f, 0.f, 0.f, 0.f};
#pragma unroll
        for (int kb = 0; kb < 4; ++kb) {
            bf16x8 bfrag = *(const bf16x8*)&WT[(size_t)(jt * 16 + l16) * K + kb * 32 + quad * 8];
            acc = __builtin_amdgcn_mfma_f32_16x16x32_bf16(afrag[kb], bfrag, acc, 0, 0, 0);
        }
        int colj = jt * 16 + l16;
#pragma unroll
        for (int r = 0; r < 4; ++r) {
            int row = base + rbase + quad * 4 + r;
            if (row < n) out[(size_t)row * M + colj] = f2bf(acc[r] * dv[r]);
        }
    }
}

// ---------------- MFMA GEMM (layers 2 / FC) ----------------
template <int K, int M, int MODE>
__global__ __launch_bounds__(256) void k_mgemm(
    const unsigned short* __restrict__ X, const unsigned short* __restrict__ WT,
    const float* __restrict__ dinv, const float* __restrict__ bias,
    void* __restrict__ outv, int n) {
    constexpr int LDW = K + 8;
    __shared__ __align__(16) unsigned short xs[64 * LDW];
    int tid = threadIdx.x;
    int base = blockIdx.x * 64;

    constexpr int C8 = K / 8;
    for (int idx = tid; idx < 64 * C8; idx += 256) {
        int r = idx / C8, c = idx - r * C8;
        int row = base + r;
        uint4 v = make_uint4(0u, 0u, 0u, 0u);
        if (row < n) v = ((const uint4*)X)[(size_t)row * C8 + c];
        *(uint4*)&xs[r * LDW + c * 8] = v;
    }
    __syncthreads();

    int wave = tid >> 6, lane = tid & 63;
    int quad = lane >> 4, l16 = lane & 15;
    int rbase = wave * 16;
    constexpr int KB = K / 32;

    bf16x8 afrag[KB];
#pragma unroll
    for (int kb = 0; kb < KB; ++kb)
        afrag[kb] = *(const bf16x8*)&xs[(rbase + l16) * LDW + kb * 32 + quad * 8];

    float dv[4];
#pragma unroll
    for (int r = 0; r < 4; ++r) {
        int row = base + rbase + quad * 4 + r;
        dv[r] = (MODE == 0 && row < n) ? dinv[row] : 0.f;
    }

#pragma unroll
    for (int jt = 0; jt < M / 16; ++jt) {
        f32x4 acc = {0.f, 0.f, 0.f, 0.f};
#pragma unroll
        for (int kb = 0; kb < KB; ++kb) {
            bf16x8 bfrag = *(const bf16x8*)&WT[(size_t)(jt * 16 + l16) * K + kb * 32 + quad * 8];
            acc = __builtin_amdgcn_mfma_f32_16x16x32_bf16(afrag[kb], bfrag, acc, 0, 0, 0);
        }
        int colj = jt * 16 + l16;
        float bv = (MODE == 1) ? bias[colj] : 0.f;
#pragma unroll
        for (int r = 0; r < 4; ++r) {
            int row = base + rbase + quad * 4 + r;
            if (row < n) {
                if constexpr (MODE == 0)
                    ((unsigned short*)outv)[(size_t)row * M + colj] = f2bf(acc[r] * dv[r]);
                else
                    ((float*)outv)[(size_t)row * M + colj] = acc[r] + bv;
            }
        }
    }
}

// ---------------- CSR aggregation (wave per node, 8-deep MLP), bf16 hs ----------------
template <int M>
__global__ void k_agg(const int* __restrict__ rowptr, const unsigned short* __restrict__ col,
                      const unsigned short* __restrict__ hs, const float* __restrict__ dinv,
                      const float* __restrict__ bias, unsigned short* __restrict__ out, int n) {
    int wave = threadIdx.x >> 6;
    int lane = threadIdx.x & 63;
    int node = blockIdx.x * 4 + wave;
    if (node >= n) return;

    int beg = rowptr[node];
    int end = rowptr[node + 1];
    float di = dinv[node];

    if constexpr (M == 128) {
        const unsigned* hp = (const unsigned*)hs;
        unsigned su = hp[(size_t)node * 64 + lane];
        float ax0 = bf16_lo(su), ay0 = bf16_hi(su);
        float ax1 = 0.f, ay1 = 0.f, ax2 = 0.f, ay2 = 0.f, ax3 = 0.f, ay3 = 0.f;
        int i = beg;
        for (; i + 7 < end; i += 8) {
            unsigned u0 = hp[(size_t)col[i]     * 64 + lane];
            unsigned u1 = hp[(size_t)col[i + 1] * 64 + lane];
            unsigned u2 = hp[(size_t)col[i + 2] * 64 + lane];
            unsigned u3 = hp[(size_t)col[i + 3] * 64 + lane];
            unsigned u4 = hp[(size_t)col[i + 4] * 64 + lane];
            unsigned u5 = hp[(size_t)col[i + 5] * 64 + lane];
            unsigned u6 = hp[(size_t)col[i + 6] * 64 + lane];
            unsigned u7 = hp[(size_t)col[i + 7] * 64 + lane];
            ax0 += bf16_lo(u0); ay0 += bf16_hi(u0);
            ax1 += bf16_lo(u1); ay1 += bf16_hi(u1);
            ax2 += bf16_lo(u2); ay2 += bf16_hi(u2);
            ax3 += bf16_lo(u3); ay3 += bf16_hi(u3);
            ax0 += bf16_lo(u4); ay0 += bf16_hi(u4);
            ax1 += bf16_lo(u5); ay1 += bf16_hi(u5);
            ax2 += bf16_lo(u6); ay2 += bf16_hi(u6);
            ax3 += bf16_lo(u7); ay3 += bf16_hi(u7);
        }
        for (; i + 3 < end; i += 4) {
            unsigned u0 = hp[(size_t)col[i]     * 64 + lane];
            unsigned u1 = hp[(size_t)col[i + 1] * 64 + lane];
            unsigned u2 = hp[(size_t)col[i + 2] * 64 + lane];
            unsigned u3 = hp[(size_t)col[i + 3] * 64 + lane];
            ax0 += bf16_lo(u0); ay0 += bf16_hi(u0);
            ax1 += bf16_lo(u1); ay1 += bf16_hi(u1);
            ax2 += bf16_lo(u2); ay2 += bf16_hi(u2);
            ax3 += bf16_lo(u3); ay3 += bf16_hi(u3);
        }
        for (; i < end; ++i) {
            unsigned u0 = hp[(size_t)col[i] * 64 + lane];
            ax0 += bf16_lo(u0); ay0 += bf16_hi(u0);
        }
        float vx = fmaxf(di * ((ax0 + ax1) + (ax2 + ax3)) + bias[2 * lane], 0.0f);
        float vy = fmaxf(di * ((ay0 + ay1) + (ay2 + ay3)) + bias[2 * lane + 1], 0.0f);
        ((unsigned*)out)[(size_t)node * 64 + lane] =
            (unsigned)f2bf(vx) | ((unsigned)f2bf(vy) << 16);
    } else {  // M == 64
        float a0 = bf16_one(hs[(size_t)node * 64 + lane]);
        float a1 = 0.f, a2 = 0.f, a3 = 0.f;
        float a4 = 0.f, a5 = 0.f, a6 = 0.f, a7 = 0.f;
        int i = beg;
        for (; i + 7 < end; i += 8) {
            a0 += bf16_one(hs[(size_t)col[i]     * 64 + lane]);
            a1 += bf16_one(hs[(size_t)col[i + 1] * 64 + lane]);
            a2 += bf16_one(hs[(size_t)col[i + 2] * 64 + lane]);
            a3 += bf16_one(hs[(size_t)col[i + 3] * 64 + lane]);
            a4 += bf16_one(hs[(size_t)col[i + 4] * 64 + lane]);
            a5 += bf16_one(hs[(size_t)col[i + 5] * 64 + lane]);
            a6 += bf16_one(hs[(size_t)col[i + 6] * 64 + lane]);
            a7 += bf16_one(hs[(size_t)col[i + 7] * 64 + lane]);
        }
        for (; i + 3 < end; i += 4) {
            a0 += bf16_one(hs[(size_t)col[i]     * 64 + lane]);
            a1 += bf16_one(hs[(size_t)col[i + 1] * 64 + lane]);
            a2 += bf16_one(hs[(size_t)col[i + 2] * 64 + lane]);
            a3 += bf16_one(hs[(size_t)col[i + 3] * 64 + lane]);
        }
        for (; i < end; ++i) a0 += bf16_one(hs[(size_t)col[i] * 64 + lane]);
        float v = fmaxf(di * (((a0 + a1) + (a2 + a3)) + ((a4 + a5) + (a6 + a7))) + bias[lane], 0.0f);
        out[(size_t)node * 64 + lane] = f2bf(v);
    }
}

// ---------------- launch ----------------

extern "C" void kernel_launch(void* const* d_in, const int* in_sizes, int n_in,
                              void* d_out, int out_size, void* d_ws, size_t ws_size,
                              hipStream_t stream) {
    const float* x   = (const float*)d_in[0];
    const int*   ei  = (const int*)d_in[1];
    const float* W1  = (const float*)d_in[2];
    const float* b1  = (const float*)d_in[3];
    const float* W2  = (const float*)d_in[4];
    const float* b2  = (const float*)d_in[5];
    const float* fcW = (const float*)d_in[6];
    const float* fcb = (const float*)d_in[7];
    float* out = (float*)d_out;

    const int N = in_sizes[0] / 128;
    const int E = in_sizes[1] / 2;
    const int* src = ei;
    const int* dst = ei + E;

    // ---- workspace carve (16B-aligned), peak ~22 MB ----
    auto align16 = [](size_t v) { return (v + 15) & ~(size_t)15; };
    char* p = (char*)d_ws;
    int* rowptr = (int*)p;                     p += align16(sizeof(int) * (N + 1));
    unsigned short* col = (unsigned short*)p;  p += align16(sizeof(unsigned short) * E);
    float* dinv = (float*)p;                   p += align16(sizeof(float) * N);
    int* degi = (int*)p;                       p += align16(sizeof(int) * N);
    int* cursor = (int*)p;                     p += align16(sizeof(int) * N);
    int* blocksum = (int*)p;                   p += align16(sizeof(int) * 256);
    unsigned short* W1T = (unsigned short*)p;  p += align16(2 * 128 * 128);
    unsigned short* W2T = (unsigned short*)p;  p += align16(2 * 64 * 128);
    unsigned short* fcWT = (unsigned short*)p; p += align16(2 * 64 * 64);
    unsigned short* hs1 = (unsigned short*)p;  p += align16(2 * (size_t)N * 128);
    unsigned short* h1  = (unsigned short*)p;  p += align16(2 * (size_t)N * 128);
    unsigned short* hs2 = (unsigned short*)p;  p += align16(2 * (size_t)N * 64);
    unsigned short* h2  = (unsigned short*)p;  p += align16(2 * (size_t)N * 64);

    const int B = 256;
    const int nb = (N + 255) / 256;
    const int gg = (N + 63) / 64;
    const int cntBlocks = (E + B - 1) / B;        // 1 edge/thread
    const int wtBlocks = (28672 + B - 1) / B;
    const int fillBlocks = (E + B - 1) / B;       // 1 edge/thread

    hipMemsetAsync(degi, 0, sizeof(int) * N, stream);
    k_count_wt<<<cntBlocks + wtBlocks, B, 0, stream>>>(dst, E, degi, W1, W2, fcW,
                                                       W1T, W2T, fcWT, cntBlocks);
    k_scan1<<<nb, 256, 0, stream>>>(degi, rowptr, blocksum, N);
    k_scan2<<<1, 256, 0, stream>>>(blocksum, nb);
    k_scan3<<<nb, 256, 0, stream>>>(rowptr, blocksum, degi, cursor, dinv, N);

    // fill + layer-1 GEMM overlapped in one dispatch
    k_fill_mg1<<<fillBlocks + gg, B, 0, stream>>>(src, dst, E, cursor, col,
                                                  x, W1T, dinv, hs1, N, fillBlocks);

    k_agg<128><<<(N + 3) / 4, 256, 0, stream>>>(rowptr, col, hs1, dinv, b1, h1, N);
    k_mgemm<128, 64, 0><<<gg, 256, 0, stream>>>(h1, W2T, dinv, nullptr, hs2, N);
    k_agg<64><<<(N + 3) / 4, 256, 0, stream>>>(rowptr, col, hs2, dinv, b2, h2, N);
    k_mgemm<64, 64, 1><<<gg, 256, 0, stream>>>(h2, fcWT, nullptr, fcb, out, N);
}